// Round 3
// baseline (266.743 us; speedup 1.0000x reference)
//
#include <hip/hip_runtime.h>

#define TPB 64
#define NITEMS (2048*128)

__global__ __launch_bounds__(TPB) void canadarm_kernel(
    const float* __restrict__ com_g,   // (B,H,3,7)  : 21 f32/item
    const float* __restrict__ pose_g,  // (B,H,4,4,9): 144 f32/item, need [r][3][l] = r*36+27+l
    const float* __restrict__ jac_g,   // (B,H,6,7)  : 42 f32/item, need first 21
    float* __restrict__ out_g)         // (B,H,6,7)  : 42 f32/item
{
    __shared__ float sh[TPB*42];       // output staging only: 10,752 B -> 14 blocks/CU
    const int tid = threadIdx.x;
    const size_t item0 = (size_t)blockIdx.x * TPB;
    const size_t item  = item0 + tid;

    const float* C  = com_g  + item*21;
    const float* P  = pose_g + item*144;
    const float* Jg = jac_g  + item*42;

    // ---- direct loads: own item's com (21 scalars; L1 dedupes lines across lanes) ----
    float com[21];
    #pragma unroll
    for (int k = 0; k < 21; ++k) com[k] = C[k];

    // ---- constants ----
    const float mass[7] = {105.98f,105.98f,314.98f,279.2f,105.98f,105.98f,243.66f};
    const float diag[7][3] = {
        {12.19f,12.19f,3.061f},
        {12.19f,12.19f,3.061f},
        {15.41f,2094.71f,2103.19f},
        {9.522f,1966.28f,1966.28f},
        {8.305f,3.061f,8.0386f},
        {12.13f,12.13f,3.061f},
        {9.336f,44.41f,44.41f}};
    float msum = 0.f;
    #pragma unroll
    for (int i = 0; i < 7; ++i) msum += mass[i];
    const float M_total = msum + 100000.0f + 243.66f;
    const float inv_M   = 1.0f / M_total;
    const float bcz     = 6.65f * (243.66f / (100000.0f + 243.66f));
    float Cd[3];
    #pragma unroll
    for (int a = 0; a < 3; ++a) {
        float s0 = 0.f;
        #pragma unroll
        for (int i = 0; i < 7; ++i) s0 += diag[i][a];
        Cd[a] = s0;
    }
    Cd[0] += 69585.02f; Cd[1] += 69585.02f; Cd[2] += 66666.664f;
    const float Kc = M_total - msum;

    // ---- system COM ----
    float rg[3];
    #pragma unroll
    for (int c = 0; c < 3; ++c) {
        float s0 = 0.f;
        #pragma unroll
        for (int i = 0; i < 7; ++i) s0 += com[c*7+i]*mass[i];
        rg[c] = s0 * inv_M;
    }
    rg[2] -= bcz;

    // ---- H_s (depends only on rg) -> symmetric analytic inverse, BEFORE the j-loop ----
    const float r2 = rg[0]*rg[0] + rg[1]*rg[1] + rg[2]*rg[2];
    const float Hs00 = Kc*(rg[0]*rg[0] - r2) + Cd[0];
    const float Hs11 = Kc*(rg[1]*rg[1] - r2) + Cd[1];
    const float Hs22 = Kc*(rg[2]*rg[2] - r2) + Cd[2];
    const float Hs01 = Kc*rg[0]*rg[1];
    const float Hs02 = Kc*rg[0]*rg[2];
    const float Hs12 = Kc*rg[1]*rg[2];
    const float A = Hs11*Hs22 - Hs12*Hs12;
    const float B = Hs12*Hs02 - Hs01*Hs22;
    const float Cc = Hs01*Hs12 - Hs11*Hs02;
    const float det = Hs00*A + Hs01*B + Hs02*Cc;
    const float id_ = 1.0f/det;
    const float Hi00 = A*id_, Hi01 = B*id_, Hi02 = Cc*id_;
    const float Hi11 = (Hs00*Hs22 - Hs02*Hs02)*id_;
    const float Hi12 = (Hs02*Hs01 - Hs00*Hs12)*id_;
    const float Hi22 = (Hs00*Hs11 - Hs01*Hs01)*id_;

    // ---- suffix loop j = 6..0: load pose_t/jac columns, emit output column j directly ----
    float w0=0.f,w1=0.f,w2=0.f, ssum=0.f;
    float M00=0.f,M01=0.f,M02=0.f,M10=0.f,M11=0.f,M12=0.f,M20=0.f,M21=0.f,M22=0.f;
    float Ds0=0.f, Ds1=0.f, Ds2=0.f;
    float* O = sh + tid*42;
    #pragma unroll
    for (int j = 6; j >= 0; --j) {
        // per-column direct loads (unrolled -> compiler hoists/batches for MLP)
        const float px = P[0*36 + 27 + j];
        const float py = P[1*36 + 27 + j];
        const float pz = P[2*36 + 27 + j];
        const float jx = Jg[0*7 + j];
        const float jy = Jg[1*7 + j];
        const float jz = Jg[2*7 + j];

        const float ax = com[0*7+j] - px;
        const float ay = com[1*7+j] - py;
        const float az = com[2*7+j] - pz;
        const float bxr = com[0*7+j];
        const float byr = com[1*7+j];
        const float bzr = com[2*7+j] - bcz;

        const float mi = mass[j];
        w0 += mi*ax; w1 += mi*ay; w2 += mi*az;
        ssum += mi*(ax*bxr + ay*byr + az*bzr);
        M00 += mi*ax*bxr; M01 += mi*ax*byr; M02 += mi*ax*bzr;
        M10 += mi*ay*bxr; M11 += mi*ay*byr; M12 += mi*ay*bzr;
        M20 += mi*az*bxr; M21 += mi*az*byr; M22 += mi*az*bzr;
        Ds0 += diag[j][0]; Ds1 += diag[j][1]; Ds2 += diag[j][2];

        const float tx = jy*w2 - jz*w1;
        const float ty = jz*w0 - jx*w2;
        const float tz = jx*w1 - jy*w0;

        const float h2x = jx*ssum - (M00*jx + M01*jy + M02*jz);
        const float h2y = jy*ssum - (M10*jx + M11*jy + M12*jz);
        const float h2z = jz*ssum - (M20*jx + M21*jy + M22*jz);

        const float cx = rg[1]*tz - rg[2]*ty;
        const float cy = rg[2]*tx - rg[0]*tz;
        const float cz = rg[0]*ty - rg[1]*tx;

        const float hx = Ds0*jx + h2x - cx;
        const float hy = Ds1*jy + h2y - cy;
        const float hz = Ds2*jz + h2z - cz;

        // bot = -Hi @ h ; top = -Jtw/M + rg x bot
        const float vx = Hi00*hx + Hi01*hy + Hi02*hz;
        const float vy = Hi01*hx + Hi11*hy + Hi12*hz;
        const float vz = Hi02*hx + Hi12*hy + Hi22*hz;
        const float bx = -vx, by = -vy, bz = -vz;

        O[0*7+j] = -tx*inv_M + (rg[1]*bz - rg[2]*by);
        O[1*7+j] = -ty*inv_M + (rg[2]*bx - rg[0]*bz);
        O[2*7+j] = -tz*inv_M + (rg[0]*by - rg[1]*bx);
        O[3*7+j] = bx;
        O[4*7+j] = by;
        O[5*7+j] = bz;
    }
    __syncthreads();

    // ---- coalesced float2 store of the block's outputs ----
    {
        const float2* so = (const float2*)sh;
        float2* dst = (float2*)(out_g + item0*42);
        #pragma unroll
        for (int i = 0; i < 21; ++i) {
            int p = tid + i*64;
            dst[p] = so[p];
        }
    }
}

extern "C" void kernel_launch(void* const* d_in, const int* in_sizes, int n_in,
                              void* d_out, int out_size, void* d_ws, size_t ws_size,
                              hipStream_t stream) {
    const float* com  = (const float*)d_in[0];
    const float* pose = (const float*)d_in[1];
    const float* jac  = (const float*)d_in[2];
    float* out = (float*)d_out;
    dim3 grid(NITEMS/TPB), block(TPB);
    hipLaunchKernelGGL(canadarm_kernel, grid, block, 0, stream, com, pose, jac, out);
}

// Round 4
// 263.748 us; speedup vs baseline: 1.0114x; 1.0114x over previous
//
#include <hip/hip_runtime.h>

#define TPB 64
#define NITEMS (2048*128)

// LDS dword layout (per 64-item block)
#define COM0  0        // 1344 dwords: com identity, 21/item
#define JAC0  1344     // 2688 dwords: full jac, 42/item (rows 0-2 used); reused for output
#define POSE0 4032     // 2304 dwords: 9 float4 chunks/item (36 dwords/item)
#define LDS_FLOATS 6336

__device__ __forceinline__ void gload16(void* lds_dst, const void* gsrc) {
    __builtin_amdgcn_global_load_lds((const __attribute__((address_space(1))) void*)gsrc,
                                     (__attribute__((address_space(3))) void*)lds_dst, 16, 0, 0);
}

__global__ __launch_bounds__(TPB) void canadarm_kernel(
    const float* __restrict__ com_g,   // (B,H,3,7)  : 21 f32/item
    const float* __restrict__ pose_g,  // (B,H,4,4,9): 144 f32/item, need [r][3][l] = r*36+27+l
    const float* __restrict__ jac_g,   // (B,H,6,7)  : 42 f32/item, need first 21
    float* __restrict__ out_g)         // (B,H,6,7)  : 42 f32/item
{
    __shared__ float sh[LDS_FLOATS];   // 25,344 B -> 6 one-wave blocks/CU
    const int tid = threadIdx.x;
    const size_t item0 = (size_t)blockIdx.x * TPB;

    // ---- com: 336 float4, fully sequential ----
    {
        const float* src = com_g + item0*21;      // 16B-aligned (5376B/block)
        #pragma unroll
        for (int i = 0; i < 5; ++i)
            gload16(&sh[COM0 + i*256], src + (size_t)(i*64 + tid)*4);
        if (tid < 16)
            gload16(&sh[COM0 + 5*256], src + (size_t)(320 + tid)*4);
    }
    // ---- jac: 672 float4, fully sequential (whole 6x7 block; rows 3-5 share lines anyway) ----
    {
        const float* src = jac_g + item0*42;      // 16B-aligned (10752B/block)
        #pragma unroll
        for (int i = 0; i < 10; ++i)
            gload16(&sh[JAC0 + i*256], src + (size_t)(i*64 + tid)*4);
        if (tid < 32)
            gload16(&sh[JAC0 + 10*256], src + (size_t)(640 + tid)*4);
    }
    // ---- pose: 576 float4 chunks, sorted; chunk c of item it at dword it*144 + (c/3)*36 + (c%3)*4 + 24 ----
    {
        const float* src = pose_g + item0*144;    // 16B-aligned (36864B/block)
        #pragma unroll
        for (int i = 0; i < 9; ++i) {
            const int q   = i*64 + tid;
            const int it  = q / 9;
            const int c   = q - it*9;
            const int run = c / 3;
            const int e   = c - run*3;
            gload16(&sh[POSE0 + i*256], src + (size_t)it*144 + run*36 + e*4 + 24);
        }
    }
    __syncthreads();   // drains vmcnt(0); single latency exposure

    // ---- own-item extraction from LDS ----
    float com[21];
    {
        const float* Lc = sh + COM0 + tid*21;     // stride 21: conflict-free
        #pragma unroll
        for (int k = 0; k < 21; ++k) com[k] = Lc[k];
    }
    float J3[3][7];
    {
        const float* Lj = sh + JAC0 + tid*42;     // stride 42: 4-way, negligible
        #pragma unroll
        for (int c = 0; c < 3; ++c)
            #pragma unroll
            for (int i = 0; i < 7; ++i) J3[c][i] = Lj[c*7 + i];
    }
    float pp[3][7];
    {
        const float* Lp = sh + POSE0 + tid*36;    // stride 36: 8-way on 21 reads, small
        #pragma unroll
        for (int c = 0; c < 3; ++c)
            #pragma unroll
            for (int l = 0; l < 7; ++l) pp[c][l] = Lp[c*12 + 3 + l];
    }

    // ---- constants ----
    const float mass[7] = {105.98f,105.98f,314.98f,279.2f,105.98f,105.98f,243.66f};
    const float diag[7][3] = {
        {12.19f,12.19f,3.061f},
        {12.19f,12.19f,3.061f},
        {15.41f,2094.71f,2103.19f},
        {9.522f,1966.28f,1966.28f},
        {8.305f,3.061f,8.0386f},
        {12.13f,12.13f,3.061f},
        {9.336f,44.41f,44.41f}};
    float msum = 0.f;
    #pragma unroll
    for (int i = 0; i < 7; ++i) msum += mass[i];
    const float M_total = msum + 100000.0f + 243.66f;
    const float inv_M   = 1.0f / M_total;
    const float bcz     = 6.65f * (243.66f / (100000.0f + 243.66f));
    float Cd[3];
    #pragma unroll
    for (int a = 0; a < 3; ++a) {
        float s0 = 0.f;
        #pragma unroll
        for (int i = 0; i < 7; ++i) s0 += diag[i][a];
        Cd[a] = s0;
    }
    Cd[0] += 69585.02f; Cd[1] += 69585.02f; Cd[2] += 66666.664f;
    const float Kc = M_total - msum;

    // ---- system COM ----
    float rg[3];
    #pragma unroll
    for (int c = 0; c < 3; ++c) {
        float s0 = 0.f;
        #pragma unroll
        for (int i = 0; i < 7; ++i) s0 += com[c*7+i]*mass[i];
        rg[c] = s0 * inv_M;
    }
    rg[2] -= bcz;

    // ---- H_s symmetric analytic inverse (depends only on rg) ----
    const float r2 = rg[0]*rg[0] + rg[1]*rg[1] + rg[2]*rg[2];
    const float Hs00 = Kc*(rg[0]*rg[0] - r2) + Cd[0];
    const float Hs11 = Kc*(rg[1]*rg[1] - r2) + Cd[1];
    const float Hs22 = Kc*(rg[2]*rg[2] - r2) + Cd[2];
    const float Hs01 = Kc*rg[0]*rg[1];
    const float Hs02 = Kc*rg[0]*rg[2];
    const float Hs12 = Kc*rg[1]*rg[2];
    const float A = Hs11*Hs22 - Hs12*Hs12;
    const float B = Hs12*Hs02 - Hs01*Hs22;
    const float Cc = Hs01*Hs12 - Hs11*Hs02;
    const float det = Hs00*A + Hs01*B + Hs02*Cc;
    const float id_ = 1.0f/det;
    const float Hi00 = A*id_, Hi01 = B*id_, Hi02 = Cc*id_;
    const float Hi11 = (Hs00*Hs22 - Hs02*Hs02)*id_;
    const float Hi12 = (Hs02*Hs01 - Hs00*Hs12)*id_;
    const float Hi22 = (Hs00*Hs11 - Hs01*Hs01)*id_;

    // ---- suffix loop j = 6..0, emit output column j into LDS (reusing jac region) ----
    float w0=0.f,w1=0.f,w2=0.f, ssum=0.f;
    float M00=0.f,M01=0.f,M02=0.f,M10=0.f,M11=0.f,M12=0.f,M20=0.f,M21=0.f,M22=0.f;
    float Ds0=0.f, Ds1=0.f, Ds2=0.f;
    float* O = sh + JAC0 + tid*42;   // overwrites only own item's jac slots (already in regs)
    #pragma unroll
    for (int j = 6; j >= 0; --j) {
        const float ax = com[0*7+j] - pp[0][j];
        const float ay = com[1*7+j] - pp[1][j];
        const float az = com[2*7+j] - pp[2][j];
        const float bxr = com[0*7+j];
        const float byr = com[1*7+j];
        const float bzr = com[2*7+j] - bcz;

        const float mi = mass[j];
        w0 += mi*ax; w1 += mi*ay; w2 += mi*az;
        ssum += mi*(ax*bxr + ay*byr + az*bzr);
        M00 += mi*ax*bxr; M01 += mi*ax*byr; M02 += mi*ax*bzr;
        M10 += mi*ay*bxr; M11 += mi*ay*byr; M12 += mi*ay*bzr;
        M20 += mi*az*bxr; M21 += mi*az*byr; M22 += mi*az*bzr;
        Ds0 += diag[j][0]; Ds1 += diag[j][1]; Ds2 += diag[j][2];

        const float jx = J3[0][j], jy = J3[1][j], jz = J3[2][j];
        const float tx = jy*w2 - jz*w1;
        const float ty = jz*w0 - jx*w2;
        const float tz = jx*w1 - jy*w0;

        const float h2x = jx*ssum - (M00*jx + M01*jy + M02*jz);
        const float h2y = jy*ssum - (M10*jx + M11*jy + M12*jz);
        const float h2z = jz*ssum - (M20*jx + M21*jy + M22*jz);

        const float cx = rg[1]*tz - rg[2]*ty;
        const float cy = rg[2]*tx - rg[0]*tz;
        const float cz = rg[0]*ty - rg[1]*tx;

        const float hx = Ds0*jx + h2x - cx;
        const float hy = Ds1*jy + h2y - cy;
        const float hz = Ds2*jz + h2z - cz;

        const float vx = Hi00*hx + Hi01*hy + Hi02*hz;
        const float vy = Hi01*hx + Hi11*hy + Hi12*hz;
        const float vz = Hi02*hx + Hi12*hy + Hi22*hz;
        const float bx = -vx, by = -vy, bz = -vz;

        O[0*7+j] = -tx*inv_M + (rg[1]*bz - rg[2]*by);
        O[1*7+j] = -ty*inv_M + (rg[2]*bx - rg[0]*bz);
        O[2*7+j] = -tz*inv_M + (rg[0]*by - rg[1]*bx);
        O[3*7+j] = bx;
        O[4*7+j] = by;
        O[5*7+j] = bz;
    }
    __syncthreads();

    // ---- coalesced float2 store of the block's outputs ----
    {
        const float2* so = (const float2*)(sh + JAC0);
        float2* dst = (float2*)(out_g + item0*42);
        #pragma unroll
        for (int i = 0; i < 21; ++i) {
            const int p = tid + i*64;
            dst[p] = so[p];
        }
    }
}

extern "C" void kernel_launch(void* const* d_in, const int* in_sizes, int n_in,
                              void* d_out, int out_size, void* d_ws, size_t ws_size,
                              hipStream_t stream) {
    const float* com  = (const float*)d_in[0];
    const float* pose = (const float*)d_in[1];
    const float* jac  = (const float*)d_in[2];
    float* out = (float*)d_out;
    dim3 grid(NITEMS/TPB), block(TPB);
    hipLaunchKernelGGL(canadarm_kernel, grid, block, 0, stream, com, pose, jac, out);
}